// Round 4
// baseline (1820.753 us; speedup 1.0000x reference)
//
#include <hip/hip_runtime.h>
#include <hip/hip_bf16.h>

#define NT 4096
#define CD 512
#define DQV 64
#define NB 4

typedef float f32x4 __attribute__((ext_vector_type(4)));
typedef short bf16x8 __attribute__((ext_vector_type(8)));
typedef short bf16x4 __attribute__((ext_vector_type(4)));

__device__ __forceinline__ short f2bf(float x){
  union { __hip_bfloat16 b; short s; } u;
  u.b = __float2bfloat16(x);
  return u.s;
}

// ---------------- weight cast fp32 -> bf16 ----------------
__global__ void cast_weights(const float* __restrict__ wq1, const float* __restrict__ wk1,
                             const float* __restrict__ wv1, const float* __restrict__ wq2,
                             const float* __restrict__ wk2, const float* __restrict__ wv2,
                             short* __restrict__ out){
  int id = blockIdx.x * 256 + threadIdx.x;
  if (id >= 655360) return;
  float v;
  if (id < 32768)        v = wq1[id];
  else if (id < 65536)   v = wk1[id - 32768];
  else if (id < 327680)  v = wv1[id - 65536];
  else if (id < 360448)  v = wq2[id - 327680];
  else if (id < 393216)  v = wk2[id - 360448];
  else                   v = wv2[id - 393216];
  out[id] = f2bf(v);
}

// ---------------- x [B,C,N] fp32 -> XT [B,N,C] bf16 ----------------
__global__ void transpose_cast(const float* __restrict__ x1, const float* __restrict__ x2,
                               short* __restrict__ XT1, short* __restrict__ XT2){
  __shared__ short t[64][66];
  int nt = blockIdx.x, ct = blockIdx.y, z = blockIdx.z;
  int b = z & 3, inp = z >> 2;
  const float* xb = (inp ? x2 : x1) + (size_t)b * CD * NT;
  short* xtb = (inp ? XT2 : XT1) + (size_t)b * NT * CD;
  int n0 = nt * 64, c0 = ct * 64;
  int tid = threadIdx.x;
  int nl = tid & 63, cl0 = (tid >> 6) * 2;
#pragma unroll
  for (int cc = 0; cc < 8; ++cc){
    int c = cl0 + cc * 8;
    float v0 = xb[(size_t)(c0 + c) * NT + n0 + nl];
    float v1 = xb[(size_t)(c0 + c + 1) * NT + n0 + nl];
    union { unsigned u; short s[2]; } p;
    p.s[0] = f2bf(v0); p.s[1] = f2bf(v1);
    *(unsigned*)&t[nl][c] = p.u;
  }
  __syncthreads();
  int cl = (tid & 31) * 2, nl0 = tid >> 5;
#pragma unroll
  for (int nn = 0; nn < 8; ++nn){
    int n = nl0 + nn * 8;
    *(unsigned*)&xtb[(size_t)(n0 + n) * CD + c0 + cl] = *(const unsigned*)&t[n][cl];
  }
}

// ---------------- Q/K projections ----------------
__global__ void proj_qk(const short* __restrict__ XT1, const short* __restrict__ XT2,
                        const short* __restrict__ WB,
                        const float* __restrict__ bq1, const float* __restrict__ bk1,
                        const float* __restrict__ bq2, const float* __restrict__ bk2,
                        short* __restrict__ Q1, short* __restrict__ K1,
                        short* __restrict__ Q2, short* __restrict__ K2){
  int pt = blockIdx.y;
  const short* xt = (pt < 2) ? XT1 : XT2;
  const short* w  = WB + (pt == 0 ? 0 : pt == 1 ? 32768 : pt == 2 ? 327680 : 360448);
  const float* bias = (pt == 0) ? bq1 : (pt == 1) ? bk1 : (pt == 2) ? bq2 : bk2;
  short* out = (pt == 0) ? Q1 : (pt == 1) ? K1 : (pt == 2) ? Q2 : K2;
  int row0 = blockIdx.x * 128;
  int wid = threadIdx.x >> 6, lane = threadIdx.x & 63;
  int lr = lane & 15, lk = (lane >> 4) * 8, lq4 = (lane >> 4) * 4;
  f32x4 acc[2][4] = {};
#pragma unroll 2
  for (int kk = 0; kk < 16; ++kk){
    int k0 = kk * 32 + lk;
    bf16x8 a[2], bb[4];
#pragma unroll
    for (int fr = 0; fr < 2; ++fr)
      a[fr] = *(const bf16x8*)&xt[(size_t)(row0 + wid*32 + fr*16 + lr) * CD + k0];
#pragma unroll
    for (int fc = 0; fc < 4; ++fc)
      bb[fc] = *(const bf16x8*)&w[(size_t)(fc*16 + lr) * CD + k0];
#pragma unroll
    for (int fr = 0; fr < 2; ++fr)
#pragma unroll
      for (int fc = 0; fc < 4; ++fc)
        acc[fr][fc] = __builtin_amdgcn_mfma_f32_16x16x32_bf16(a[fr], bb[fc], acc[fr][fc], 0,0,0);
  }
#pragma unroll
  for (int fr = 0; fr < 2; ++fr)
#pragma unroll
    for (int fc = 0; fc < 4; ++fc){
      int col = fc*16 + lr;
      float bsv = bias[col];
#pragma unroll
      for (int r = 0; r < 4; ++r){
        int row = row0 + wid*32 + fr*16 + lq4 + r;
        out[(size_t)row * DQV + col] = f2bf(acc[fr][fc][r] + bsv);
      }
    }
}

// ---------------- V projection ----------------
__global__ void proj_v(const short* __restrict__ XT1, const short* __restrict__ XT2,
                       const short* __restrict__ WB,
                       const float* __restrict__ bv1, const float* __restrict__ bv2,
                       short* __restrict__ V1, short* __restrict__ V2){
  int inp = blockIdx.z, b = blockIdx.y;
  int ct = blockIdx.x >> 6, nt = blockIdx.x & 63;
  const short* xt = (inp ? XT2 : XT1) + (size_t)b * NT * CD;
  const short* w  = WB + (inp ? 393216 : 65536);
  const float* bias = inp ? bv2 : bv1;
  short* V = (inp ? V2 : V1) + (size_t)b * CD * NT;
  int c0 = ct * 128, n0 = nt * 64;
  int wid = threadIdx.x >> 6, lane = threadIdx.x & 63;
  int ch = wid >> 1, nh = wid & 1;
  int lr = lane & 15, lk = (lane >> 4) * 8, lq4 = (lane >> 4) * 4;
  f32x4 acc[4][2] = {};
#pragma unroll 2
  for (int kk = 0; kk < 16; ++kk){
    int k0 = kk * 32 + lk;
    bf16x8 a[4], bb[2];
#pragma unroll
    for (int fr = 0; fr < 4; ++fr)
      a[fr] = *(const bf16x8*)&w[(size_t)(c0 + ch*64 + fr*16 + lr) * CD + k0];
#pragma unroll
    for (int fc = 0; fc < 2; ++fc)
      bb[fc] = *(const bf16x8*)&xt[(size_t)(n0 + nh*32 + fc*16 + lr) * CD + k0];
#pragma unroll
    for (int fr = 0; fr < 4; ++fr)
#pragma unroll
      for (int fc = 0; fc < 2; ++fc)
        acc[fr][fc] = __builtin_amdgcn_mfma_f32_16x16x32_bf16(a[fr], bb[fc], acc[fr][fc], 0,0,0);
  }
#pragma unroll
  for (int fr = 0; fr < 4; ++fr)
#pragma unroll
    for (int fc = 0; fc < 2; ++fc)
#pragma unroll
      for (int r = 0; r < 4; ++r){
        int c = c0 + ch*64 + fr*16 + lq4 + r;
        int n = n0 + nh*32 + fc*16 + lr;
        V[(size_t)c * NT + n] = f2bf(acc[fr][fc][r] + bias[c]);
      }
}

// ---------------- fused flash cross-attention + residual ----------------
// 1024 blocks x 512 threads: 32 queries/block, 4 blocks/CU = 32 waves/CU (100% occupancy),
// 4 independent barrier domains per CU. 2 barriers/KV-tile (third proved redundant:
// single S/P buffers are race-free under the bar1/bar2 pattern). V frags issued at loop
// top (consumed post-bar2, ~full phase of latency cover); K frags prefetched 1 tile ahead.
__global__ void __launch_bounds__(512, 8) attn_fused(
    const short* __restrict__ Q1, const short* __restrict__ K1, const short* __restrict__ V1,
    const short* __restrict__ Q2, const short* __restrict__ K2, const short* __restrict__ V2,
    const float* __restrict__ x1, const float* __restrict__ x2,
    const float* __restrict__ g1, const float* __restrict__ g2,
    float* __restrict__ out){
  __shared__ float S[32][69];          // odd word-stride: conflict-free scalar softmax reads
  __shared__ __align__(16) short P[32][80];  // 160B rows: 16B-aligned b128 reads
  __shared__ float lrow[32], crow[32];

  int bid = blockIdx.x;
  int pair = bid & 7, qb = bid >> 3;   // pair -> XCD affinity; qb in [0,128)
  int b = pair & 3, at = pair >> 2;
  const short* Q = at ? Q2 : Q1;
  const short* K = at ? K1 : K2;
  const short* V = at ? V1 : V2;
  const float* xr = at ? x2 : x1;
  float gamma = at ? g2[0] : g1[0];
  float* outp = out + (size_t)at * NB*CD*NT + (size_t)b * CD*NT;
  const float* xrb = xr + (size_t)b * CD*NT;
  const short* Qb = Q + ((size_t)b*NT + (size_t)qb*32) * DQV;
  const short* Kb = K + (size_t)b*NT*DQV;
  const short* Vb = V + (size_t)b*CD*NT;

  int tid = threadIdx.x, wid = tid >> 6, lane = tid & 63;
  int lr = lane & 15, lk8 = (lane >> 4) * 8, lq4 = (lane >> 4) * 4;

  // QK role: wave (rh,cb) computes S[rh*16..+15][cb*16..+15]
  int rh = wid >> 2, cb = wid & 3;
  bf16x8 qf[2];
#pragma unroll
  for (int fk = 0; fk < 2; ++fk)
    qf[fk] = *(const bf16x8*)&Qb[(size_t)(rh*16 + lr) * DQV + fk*32 + lk8];

  f32x4 acc[4][2] = {};                // PV: wave owns 64 channels x 32 queries
  int c0 = wid * 64;
  int si = tid >> 4, sj = (tid & 15) * 4;  // softmax: 16 threads/row, 4 vals each
  float m_reg = -1e30f, l_reg = 0.f;

  // K prefetch for tile 0
  bf16x8 kf0 = *(const bf16x8*)&Kb[(size_t)(cb*16 + lr) * DQV + lk8];
  bf16x8 kf1 = *(const bf16x8*)&Kb[(size_t)(cb*16 + lr) * DQV + 32 + lk8];

#pragma unroll 1
  for (int jt = 0; jt < 64; ++jt){
    int j0 = jt * 64;
    // ---- issue V loads for this tile (consumed after bar2) ----
    bf16x8 vf[4][2];
#pragma unroll
    for (int cr = 0; cr < 4; ++cr)
#pragma unroll
      for (int kk = 0; kk < 2; ++kk)
        vf[cr][kk] = *(const bf16x8*)&Vb[(size_t)(c0 + cr*16 + lr) * NT + j0 + kk*32 + lk8];
    // ---- QK^T tile (prefetched K) ----
    f32x4 s0 = {};
    s0 = __builtin_amdgcn_mfma_f32_16x16x32_bf16(qf[0], kf0, s0, 0,0,0);
    s0 = __builtin_amdgcn_mfma_f32_16x16x32_bf16(qf[1], kf1, s0, 0,0,0);
    // prefetch K for next tile
    if (jt < 63){
      kf0 = *(const bf16x8*)&Kb[(size_t)(j0 + 64 + cb*16 + lr) * DQV + lk8];
      kf1 = *(const bf16x8*)&Kb[(size_t)(j0 + 64 + cb*16 + lr) * DQV + 32 + lk8];
    }
#pragma unroll
    for (int r = 0; r < 4; ++r)
      S[rh*16 + lq4 + r][cb*16 + lr] = s0[r];
    __syncthreads();
    // ---- online softmax: max, P = exp(S-m) bf16, row sum ----
    {
      float v0 = S[si][sj], v1 = S[si][sj+1], v2 = S[si][sj+2], v3 = S[si][sj+3];
      float mx = fmaxf(fmaxf(v0, v1), fmaxf(v2, v3));
      mx = fmaxf(mx, __shfl_xor(mx, 1));
      mx = fmaxf(mx, __shfl_xor(mx, 2));
      mx = fmaxf(mx, __shfl_xor(mx, 4));
      mx = fmaxf(mx, __shfl_xor(mx, 8));
      float mn = fmaxf(m_reg, mx);
      float cf = __expf(m_reg - mn);   // no-growth => exactly 1.0
      float e0 = __expf(v0 - mn), e1 = __expf(v1 - mn);
      float e2 = __expf(v2 - mn), e3 = __expf(v3 - mn);
      float sum = (e0 + e1) + (e2 + e3);
      bf16x4 pv;
      pv[0] = f2bf(e0); pv[1] = f2bf(e1); pv[2] = f2bf(e2); pv[3] = f2bf(e3);
      *(bf16x4*)&P[si][sj] = pv;
      sum += __shfl_xor(sum, 1);
      sum += __shfl_xor(sum, 2);
      sum += __shfl_xor(sum, 4);
      sum += __shfl_xor(sum, 8);
      l_reg = l_reg * cf + sum;
      m_reg = mn;
      if ((tid & 15) == 0) crow[si] = cf;
    }
    __syncthreads();
    // ---- rescale accumulators (exact skip when all cf==1), PV MFMA ----
    {
      float cf0 = crow[lr], cf1 = crow[16 + lr];
      bool ident = (cf0 == 1.f) & (cf1 == 1.f);
      if (!__all(ident)){
#pragma unroll
        for (int cr = 0; cr < 4; ++cr){
          acc[cr][0][0] *= cf0; acc[cr][0][1] *= cf0; acc[cr][0][2] *= cf0; acc[cr][0][3] *= cf0;
          acc[cr][1][0] *= cf1; acc[cr][1][1] *= cf1; acc[cr][1][2] *= cf1; acc[cr][1][3] *= cf1;
        }
      }
    }
    __builtin_amdgcn_s_setprio(1);
#pragma unroll
    for (int kk = 0; kk < 2; ++kk){
      bf16x8 pf[2];
#pragma unroll
      for (int ci = 0; ci < 2; ++ci)
        pf[ci] = *(const bf16x8*)&P[ci*16 + lr][kk*32 + lk8];
#pragma unroll
      for (int cr = 0; cr < 4; ++cr)
#pragma unroll
        for (int ci = 0; ci < 2; ++ci)
          acc[cr][ci] = __builtin_amdgcn_mfma_f32_16x16x32_bf16(vf[cr][kk], pf[ci], acc[cr][ci], 0,0,0);
    }
    __builtin_amdgcn_s_setprio(0);
    // no third barrier: next-iter S writes are post-bar2 for all waves; P(t+1)
    // writes occur only after bar1(t+1), which requires all waves to finish PV(t).
  }
  // ---- publish row sums, epilogue: out = x + gamma * acc / l ----
  if ((tid & 15) == 0) lrow[si] = l_reg;
  __syncthreads();
#pragma unroll
  for (int ci = 0; ci < 2; ++ci){
    float linv = 1.f / lrow[ci*16 + lr];
    int ig = qb*32 + ci*16 + lr;
#pragma unroll
    for (int cr = 0; cr < 4; ++cr)
#pragma unroll
      for (int r = 0; r < 4; ++r){
        int c = c0 + cr*16 + lq4 + r;
        size_t idx = (size_t)c * NT + ig;
        outp[idx] = xrb[idx] + gamma * acc[cr][ci][r] * linv;
      }
  }
}

extern "C" void kernel_launch(void* const* d_in, const int* in_sizes, int n_in,
                              void* d_out, int out_size, void* d_ws, size_t ws_size,
                              hipStream_t stream) {
  const float* x1  = (const float*)d_in[0];
  const float* x2  = (const float*)d_in[1];
  const float* wq1 = (const float*)d_in[2];
  const float* bq1 = (const float*)d_in[3];
  const float* wk1 = (const float*)d_in[4];
  const float* bk1 = (const float*)d_in[5];
  const float* wv1 = (const float*)d_in[6];
  const float* bv1 = (const float*)d_in[7];
  const float* wq2 = (const float*)d_in[8];
  const float* bq2 = (const float*)d_in[9];
  const float* wk2 = (const float*)d_in[10];
  const float* bk2 = (const float*)d_in[11];
  const float* wv2 = (const float*)d_in[12];
  const float* bv2 = (const float*)d_in[13];
  const float* g1  = (const float*)d_in[14];
  const float* g2  = (const float*)d_in[15];

  short* XT1 = (short*)d_ws;               // [4,4096,512]
  short* XT2 = XT1 + 8388608;
  short* Q1  = XT2 + 8388608;              // [4*4096,64]
  short* K1  = Q1 + 1048576;
  short* Q2  = K1 + 1048576;
  short* K2  = Q2 + 1048576;
  short* V1  = K2 + 1048576;               // [4,512,4096]
  short* V2  = V1 + 8388608;
  short* WB  = V2 + 8388608;               // cast weights

  cast_weights<<<2560, 256, 0, stream>>>(wq1, wk1, wv1, wq2, wk2, wv2, WB);
  transpose_cast<<<dim3(64, 8, 8), 256, 0, stream>>>(x1, x2, XT1, XT2);
  proj_qk<<<dim3(128, 4), 256, 0, stream>>>(XT1, XT2, WB, bq1, bk1, bq2, bk2, Q1, K1, Q2, K2);
  proj_v<<<dim3(256, 4, 2), 256, 0, stream>>>(XT1, XT2, WB, bv1, bv2, V1, V2);
  attn_fused<<<1024, 512, 0, stream>>>(Q1, K1, V1, Q2, K2, V2, x1, x2, g1, g2, (float*)d_out);
}

// Round 5
// 776.211 us; speedup vs baseline: 2.3457x; 2.3457x over previous
//
#include <hip/hip_runtime.h>
#include <hip/hip_bf16.h>

#define NT 4096
#define CD 512
#define DQV 64
#define NB 4

typedef float f32x4 __attribute__((ext_vector_type(4)));
typedef short bf16x8 __attribute__((ext_vector_type(8)));

__device__ __forceinline__ short f2bf(float x){
  union { __hip_bfloat16 b; short s; } u;
  u.b = __float2bfloat16(x);
  return u.s;
}

// ---------------- weight cast fp32 -> bf16 ----------------
__global__ void cast_weights(const float* __restrict__ wq1, const float* __restrict__ wk1,
                             const float* __restrict__ wv1, const float* __restrict__ wq2,
                             const float* __restrict__ wk2, const float* __restrict__ wv2,
                             short* __restrict__ out){
  int id = blockIdx.x * 256 + threadIdx.x;
  if (id >= 655360) return;
  float v;
  if (id < 32768)        v = wq1[id];
  else if (id < 65536)   v = wk1[id - 32768];
  else if (id < 327680)  v = wv1[id - 65536];
  else if (id < 360448)  v = wq2[id - 327680];
  else if (id < 393216)  v = wk2[id - 360448];
  else                   v = wv2[id - 393216];
  out[id] = f2bf(v);
}

// ---------------- x [B,C,N] fp32 -> XT [B,N,C] bf16 ----------------
__global__ void transpose_cast(const float* __restrict__ x1, const float* __restrict__ x2,
                               short* __restrict__ XT1, short* __restrict__ XT2){
  __shared__ short t[64][66];
  int nt = blockIdx.x, ct = blockIdx.y, z = blockIdx.z;
  int b = z & 3, inp = z >> 2;
  const float* xb = (inp ? x2 : x1) + (size_t)b * CD * NT;
  short* xtb = (inp ? XT2 : XT1) + (size_t)b * NT * CD;
  int n0 = nt * 64, c0 = ct * 64;
  int tid = threadIdx.x;
  int nl = tid & 63, cl0 = (tid >> 6) * 2;
#pragma unroll
  for (int cc = 0; cc < 8; ++cc){
    int c = cl0 + cc * 8;
    float v0 = xb[(size_t)(c0 + c) * NT + n0 + nl];
    float v1 = xb[(size_t)(c0 + c + 1) * NT + n0 + nl];
    union { unsigned u; short s[2]; } p;
    p.s[0] = f2bf(v0); p.s[1] = f2bf(v1);
    *(unsigned*)&t[nl][c] = p.u;
  }
  __syncthreads();
  int cl = (tid & 31) * 2, nl0 = tid >> 5;
#pragma unroll
  for (int nn = 0; nn < 8; ++nn){
    int n = nl0 + nn * 8;
    *(unsigned*)&xtb[(size_t)(n0 + n) * CD + c0 + cl] = *(const unsigned*)&t[n][cl];
  }
}

// ---------------- Q/K projections ----------------
__global__ void proj_qk(const short* __restrict__ XT1, const short* __restrict__ XT2,
                        const short* __restrict__ WB,
                        const float* __restrict__ bq1, const float* __restrict__ bk1,
                        const float* __restrict__ bq2, const float* __restrict__ bk2,
                        short* __restrict__ Q1, short* __restrict__ K1,
                        short* __restrict__ Q2, short* __restrict__ K2){
  int pt = blockIdx.y;
  const short* xt = (pt < 2) ? XT1 : XT2;
  const short* w  = WB + (pt == 0 ? 0 : pt == 1 ? 32768 : pt == 2 ? 327680 : 360448);
  const float* bias = (pt == 0) ? bq1 : (pt == 1) ? bk1 : (pt == 2) ? bq2 : bk2;
  short* out = (pt == 0) ? Q1 : (pt == 1) ? K1 : (pt == 2) ? Q2 : K2;
  int row0 = blockIdx.x * 128;
  int wid = threadIdx.x >> 6, lane = threadIdx.x & 63;
  int lr = lane & 15, lk = (lane >> 4) * 8, lq4 = (lane >> 4) * 4;
  f32x4 acc[2][4] = {};
#pragma unroll 2
  for (int kk = 0; kk < 16; ++kk){
    int k0 = kk * 32 + lk;
    bf16x8 a[2], bb[4];
#pragma unroll
    for (int fr = 0; fr < 2; ++fr)
      a[fr] = *(const bf16x8*)&xt[(size_t)(row0 + wid*32 + fr*16 + lr) * CD + k0];
#pragma unroll
    for (int fc = 0; fc < 4; ++fc)
      bb[fc] = *(const bf16x8*)&w[(size_t)(fc*16 + lr) * CD + k0];
#pragma unroll
    for (int fr = 0; fr < 2; ++fr)
#pragma unroll
      for (int fc = 0; fc < 4; ++fc)
        acc[fr][fc] = __builtin_amdgcn_mfma_f32_16x16x32_bf16(a[fr], bb[fc], acc[fr][fc], 0,0,0);
  }
#pragma unroll
  for (int fr = 0; fr < 2; ++fr)
#pragma unroll
    for (int fc = 0; fc < 4; ++fc){
      int col = fc*16 + lr;
      float bsv = bias[col];
#pragma unroll
      for (int r = 0; r < 4; ++r){
        int row = row0 + wid*32 + fr*16 + lq4 + r;
        out[(size_t)row * DQV + col] = f2bf(acc[fr][fc][r] + bsv);
      }
    }
}

// ---------------- V projection ----------------
__global__ void proj_v(const short* __restrict__ XT1, const short* __restrict__ XT2,
                       const short* __restrict__ WB,
                       const float* __restrict__ bv1, const float* __restrict__ bv2,
                       short* __restrict__ V1, short* __restrict__ V2){
  int inp = blockIdx.z, b = blockIdx.y;
  int ct = blockIdx.x >> 6, nt = blockIdx.x & 63;
  const short* xt = (inp ? XT2 : XT1) + (size_t)b * NT * CD;
  const short* w  = WB + (inp ? 393216 : 65536);
  const float* bias = inp ? bv2 : bv1;
  short* V = (inp ? V2 : V1) + (size_t)b * CD * NT;
  int c0 = ct * 128, n0 = nt * 64;
  int wid = threadIdx.x >> 6, lane = threadIdx.x & 63;
  int ch = wid >> 1, nh = wid & 1;
  int lr = lane & 15, lk = (lane >> 4) * 8, lq4 = (lane >> 4) * 4;
  f32x4 acc[4][2] = {};
#pragma unroll 2
  for (int kk = 0; kk < 16; ++kk){
    int k0 = kk * 32 + lk;
    bf16x8 a[4], bb[2];
#pragma unroll
    for (int fr = 0; fr < 4; ++fr)
      a[fr] = *(const bf16x8*)&w[(size_t)(c0 + ch*64 + fr*16 + lr) * CD + k0];
#pragma unroll
    for (int fc = 0; fc < 2; ++fc)
      bb[fc] = *(const bf16x8*)&xt[(size_t)(n0 + nh*32 + fc*16 + lr) * CD + k0];
#pragma unroll
    for (int fr = 0; fr < 4; ++fr)
#pragma unroll
      for (int fc = 0; fc < 2; ++fc)
        acc[fr][fc] = __builtin_amdgcn_mfma_f32_16x16x32_bf16(a[fr], bb[fc], acc[fr][fc], 0,0,0);
  }
#pragma unroll
  for (int fr = 0; fr < 4; ++fr)
#pragma unroll
    for (int fc = 0; fc < 2; ++fc)
#pragma unroll
      for (int r = 0; r < 4; ++r){
        int c = c0 + ch*64 + fr*16 + lq4 + r;
        int n = n0 + nh*32 + fc*16 + lr;
        V[(size_t)c * NT + n] = f2bf(acc[fr][fc][r] + bias[c]);
      }
}

// ---------------- fused flash cross-attention + residual ----------------
// ROUND-3 GEOMETRY RESTORED (traffic-optimal): 512 blocks x 512 thr, 64 queries/block,
// 2 blocks/CU. Round-4 lesson: more blocks/pair => V re-read traffic explodes past L2
// (0.16GB -> 7.15GB HBM). This round: KVBLK=128 (half the iterations) + 2 barriers/iter
// (third proven redundant) => 64 barriers/block vs round-3's 192, same V traffic.
// __launch_bounds__(512,4): pin allocator to 128 unified regs (64 VGPR + 64 AGPR acc).
__global__ void __launch_bounds__(512, 4) attn_fused(
    const short* __restrict__ Q1, const short* __restrict__ K1, const short* __restrict__ V1,
    const short* __restrict__ Q2, const short* __restrict__ K2, const short* __restrict__ V2,
    const float* __restrict__ x1, const float* __restrict__ x2,
    const float* __restrict__ g1, const float* __restrict__ g2,
    float* __restrict__ out){
  __shared__ float S[64][132];               // 132 words % 32 = 4: <=2-way on frag access
  __shared__ __align__(16) short P[64][136]; // 68 words % 32 = 4; 272B rows (16B aligned)
  __shared__ float lrow[64], crow[64];

  int bid = blockIdx.x;
  int pair = bid & 7, qb = bid >> 3;   // pair -> XCD affinity; qb in [0,64)
  int b = pair & 3, at = pair >> 2;
  const short* Q = at ? Q2 : Q1;
  const short* K = at ? K1 : K2;   // cross: queries from one stream, K/V from the other
  const short* V = at ? V1 : V2;
  const float* xr = at ? x2 : x1;
  float gamma = at ? g2[0] : g1[0];
  float* outp = out + (size_t)at * NB*CD*NT + (size_t)b * CD*NT;
  const float* xrb = xr + (size_t)b * CD*NT;
  const short* Qb = Q + ((size_t)b*NT + (size_t)qb*64) * DQV;
  const short* Kb = K + (size_t)b*NT*DQV;
  const short* Vb = V + (size_t)b*CD*NT;

  int tid = threadIdx.x, wid = tid >> 6, lane = tid & 63;
  int lr = lane & 15, lk8 = (lane >> 4) * 8, lq4 = (lane >> 4) * 4;

  // QK role: wave (rh,cb) computes S[rh*32..+31][cb*32..+31]
  int rh = wid >> 2, cb = wid & 3;
  bf16x8 qf[2][2];
#pragma unroll
  for (int fr = 0; fr < 2; ++fr)
#pragma unroll
    for (int fk = 0; fk < 2; ++fk)
      qf[fr][fk] = *(const bf16x8*)&Qb[(size_t)(rh*32 + fr*16 + lr) * DQV + fk*32 + lk8];

  f32x4 acc[4][4] = {};                // PV: wave owns 64 channels x 64 queries
  int c0 = wid * 64;
  int si = tid >> 3, sj = (tid & 7) * 16;  // softmax: 8 threads/row, 16 vals each
  float m_reg = -1e30f, l_reg = 0.f;

#pragma unroll 1
  for (int jt = 0; jt < 32; ++jt){
    int j0 = jt * 128;
    // ---- QK^T tile: 64 queries x 128 keys ----
    f32x4 s[2][2] = {};
    bf16x8 kf[2][2];
#pragma unroll
    for (int fc = 0; fc < 2; ++fc)
#pragma unroll
      for (int fk = 0; fk < 2; ++fk)
        kf[fc][fk] = *(const bf16x8*)&Kb[(size_t)(j0 + cb*32 + fc*16 + lr) * DQV + fk*32 + lk8];
#pragma unroll
    for (int fr = 0; fr < 2; ++fr)
#pragma unroll
      for (int fc = 0; fc < 2; ++fc){
        s[fr][fc] = __builtin_amdgcn_mfma_f32_16x16x32_bf16(qf[fr][0], kf[fc][0], s[fr][fc], 0,0,0);
        s[fr][fc] = __builtin_amdgcn_mfma_f32_16x16x32_bf16(qf[fr][1], kf[fc][1], s[fr][fc], 0,0,0);
      }
#pragma unroll
    for (int fr = 0; fr < 2; ++fr)
#pragma unroll
      for (int fc = 0; fc < 2; ++fc)
#pragma unroll
        for (int r = 0; r < 4; ++r)
          S[rh*32 + fr*16 + lq4 + r][cb*32 + fc*16 + lr] = s[fr][fc][r];
    __syncthreads();
    // ---- online softmax over 128 cols: max, P=exp(S-m) bf16, row sum ----
    {
      f32x4 a0 = *(const f32x4*)&S[si][sj];
      f32x4 a1 = *(const f32x4*)&S[si][sj + 4];
      f32x4 a2 = *(const f32x4*)&S[si][sj + 8];
      f32x4 a3 = *(const f32x4*)&S[si][sj + 12];
      float mx = fmaxf(fmaxf(fmaxf(a0[0],a0[1]),fmaxf(a0[2],a0[3])),
                       fmaxf(fmaxf(a1[0],a1[1]),fmaxf(a1[2],a1[3])));
      mx = fmaxf(mx, fmaxf(fmaxf(fmaxf(a2[0],a2[1]),fmaxf(a2[2],a2[3])),
                           fmaxf(fmaxf(a3[0],a3[1]),fmaxf(a3[2],a3[3]))));
      mx = fmaxf(mx, __shfl_xor(mx, 1));
      mx = fmaxf(mx, __shfl_xor(mx, 2));
      mx = fmaxf(mx, __shfl_xor(mx, 4));
      float mn = fmaxf(m_reg, mx);
      float cf = __expf(m_reg - mn);   // no-growth => exactly 1.0
      bf16x8 p0, p1;
      float sum = 0.f;
#pragma unroll
      for (int t = 0; t < 4; ++t){
        float e = __expf(a0[t] - mn); sum += e; p0[t] = f2bf(e);
      }
#pragma unroll
      for (int t = 0; t < 4; ++t){
        float e = __expf(a1[t] - mn); sum += e; p0[4+t] = f2bf(e);
      }
#pragma unroll
      for (int t = 0; t < 4; ++t){
        float e = __expf(a2[t] - mn); sum += e; p1[t] = f2bf(e);
      }
#pragma unroll
      for (int t = 0; t < 4; ++t){
        float e = __expf(a3[t] - mn); sum += e; p1[4+t] = f2bf(e);
      }
      *(bf16x8*)&P[si][sj]     = p0;
      *(bf16x8*)&P[si][sj + 8] = p1;
      sum += __shfl_xor(sum, 1);
      sum += __shfl_xor(sum, 2);
      sum += __shfl_xor(sum, 4);
      l_reg = l_reg * cf + sum;
      m_reg = mn;
      if ((tid & 7) == 0) crow[si] = cf;
    }
    __syncthreads();
    // ---- rescale accumulators (exact skip when all cf==1), PV MFMA ----
    {
      float cfa[4];
#pragma unroll
      for (int ci = 0; ci < 4; ++ci) cfa[ci] = crow[ci*16 + lr];
      bool ident = (cfa[0] == 1.f) & (cfa[1] == 1.f) & (cfa[2] == 1.f) & (cfa[3] == 1.f);
      if (!__all(ident)){
#pragma unroll
        for (int ci = 0; ci < 4; ++ci){
          float cf = cfa[ci];
#pragma unroll
          for (int cr = 0; cr < 4; ++cr){
            acc[cr][ci][0] *= cf; acc[cr][ci][1] *= cf;
            acc[cr][ci][2] *= cf; acc[cr][ci][3] *= cf;
          }
        }
      }
    }
    __builtin_amdgcn_s_setprio(1);
#pragma unroll
    for (int kk = 0; kk < 4; ++kk){
      bf16x8 pf[4];
#pragma unroll
      for (int ci = 0; ci < 4; ++ci)
        pf[ci] = *(const bf16x8*)&P[ci*16 + lr][kk*32 + lk8];
#pragma unroll
      for (int cr = 0; cr < 4; ++cr){
        bf16x8 vf = *(const bf16x8*)&Vb[(size_t)(c0 + cr*16 + lr) * NT + j0 + kk*32 + lk8];
#pragma unroll
        for (int ci = 0; ci < 4; ++ci)
          acc[cr][ci] = __builtin_amdgcn_mfma_f32_16x16x32_bf16(vf, pf[ci], acc[cr][ci], 0,0,0);
      }
    }
    __builtin_amdgcn_s_setprio(0);
    // no third barrier: S(t+1)/P(t+1) writes are ordered behind bar1(t+1)/bar2(t+1)
  }
  // ---- publish row sums, epilogue: out = x + gamma * acc / l ----
  if ((tid & 7) == 0) lrow[si] = l_reg;
  __syncthreads();
#pragma unroll
  for (int ci = 0; ci < 4; ++ci){
    float linv = 1.f / lrow[ci*16 + lr];
    int ig = qb*64 + ci*16 + lr;
#pragma unroll
    for (int cr = 0; cr < 4; ++cr)
#pragma unroll
      for (int r = 0; r < 4; ++r){
        int c = c0 + cr*16 + lq4 + r;
        size_t idx = (size_t)c * NT + ig;
        outp[idx] = xrb[idx] + gamma * acc[cr][ci][r] * linv;
      }
  }
}

extern "C" void kernel_launch(void* const* d_in, const int* in_sizes, int n_in,
                              void* d_out, int out_size, void* d_ws, size_t ws_size,
                              hipStream_t stream) {
  const float* x1  = (const float*)d_in[0];
  const float* x2  = (const float*)d_in[1];
  const float* wq1 = (const float*)d_in[2];
  const float* bq1 = (const float*)d_in[3];
  const float* wk1 = (const float*)d_in[4];
  const float* bk1 = (const float*)d_in[5];
  const float* wv1 = (const float*)d_in[6];
  const float* bv1 = (const float*)d_in[7];
  const float* wq2 = (const float*)d_in[8];
  const float* bq2 = (const float*)d_in[9];
  const float* wk2 = (const float*)d_in[10];
  const float* bk2 = (const float*)d_in[11];
  const float* wv2 = (const float*)d_in[12];
  const float* bv2 = (const float*)d_in[13];
  const float* g1  = (const float*)d_in[14];
  const float* g2  = (const float*)d_in[15];

  short* XT1 = (short*)d_ws;               // [4,4096,512]
  short* XT2 = XT1 + 8388608;
  short* Q1  = XT2 + 8388608;              // [4*4096,64]
  short* K1  = Q1 + 1048576;
  short* Q2  = K1 + 1048576;
  short* K2  = Q2 + 1048576;
  short* V1  = K2 + 1048576;               // [4,512,4096]
  short* V2  = V1 + 8388608;
  short* WB  = V2 + 8388608;               // cast weights

  cast_weights<<<2560, 256, 0, stream>>>(wq1, wk1, wv1, wq2, wk2, wv2, WB);
  transpose_cast<<<dim3(64, 8, 8), 256, 0, stream>>>(x1, x2, XT1, XT2);
  proj_qk<<<dim3(128, 4), 256, 0, stream>>>(XT1, XT2, WB, bq1, bk1, bq2, bk2, Q1, K1, Q2, K2);
  proj_v<<<dim3(256, 4, 2), 256, 0, stream>>>(XT1, XT2, WB, bv1, bv2, V1, V2);
  attn_fused<<<512, 512, 0, stream>>>(Q1, K1, V1, Q2, K2, V2, x1, x2, g1, g2, (float*)d_out);
}

// Round 8
// 621.275 us; speedup vs baseline: 2.9307x; 1.2494x over previous
//
#include <hip/hip_runtime.h>
#include <hip/hip_bf16.h>

#define NT 4096
#define CD 512
#define DQV 64
#define NB 4

typedef float f32x4 __attribute__((ext_vector_type(4)));
typedef short bf16x8 __attribute__((ext_vector_type(8)));

__device__ __forceinline__ short f2bf(float x){
  union { __hip_bfloat16 b; short s; } u;
  u.b = __float2bfloat16(x);
  return u.s;
}

// raw barrier: LDS ordering only (lgkmcnt), deliberately NO vmcnt drain so global
// loads (V prefetch) stay in flight across it. Memory-clobber on BOTH sides:
// s_barrier is not an LLVM memory fence, so without the trailing clobber the
// compiler may hoist post-barrier ds_reads above it (rule-18-class hazard).
#define BAR() do { asm volatile("s_waitcnt lgkmcnt(0)" ::: "memory"); \
                   __builtin_amdgcn_s_barrier(); \
                   asm volatile("" ::: "memory"); } while(0)

// ---------------- weight cast fp32 -> bf16 ----------------
__global__ void cast_weights(const float* __restrict__ wq1, const float* __restrict__ wk1,
                             const float* __restrict__ wv1, const float* __restrict__ wq2,
                             const float* __restrict__ wk2, const float* __restrict__ wv2,
                             short* __restrict__ out){
  int id = blockIdx.x * 256 + threadIdx.x;
  if (id >= 655360) return;
  float v;
  if (id < 32768)        v = wq1[id];
  else if (id < 65536)   v = wk1[id - 32768];
  else if (id < 327680)  v = wv1[id - 65536];
  else if (id < 360448)  v = wq2[id - 327680];
  else if (id < 393216)  v = wk2[id - 360448];
  else                   v = wv2[id - 393216];
  out[id] = f2bf(v);
}

// ---------------- x [B,C,N] fp32 -> XT [B,N,C] bf16 ----------------
__global__ void transpose_cast(const float* __restrict__ x1, const float* __restrict__ x2,
                               short* __restrict__ XT1, short* __restrict__ XT2){
  __shared__ short t[64][66];
  int nt = blockIdx.x, ct = blockIdx.y, z = blockIdx.z;
  int b = z & 3, inp = z >> 2;
  const float* xb = (inp ? x2 : x1) + (size_t)b * CD * NT;
  short* xtb = (inp ? XT2 : XT1) + (size_t)b * NT * CD;
  int n0 = nt * 64, c0 = ct * 64;
  int tid = threadIdx.x;
  int nl = tid & 63, cl0 = (tid >> 6) * 2;
#pragma unroll
  for (int cc = 0; cc < 8; ++cc){
    int c = cl0 + cc * 8;
    float v0 = xb[(size_t)(c0 + c) * NT + n0 + nl];
    float v1 = xb[(size_t)(c0 + c + 1) * NT + n0 + nl];
    union { unsigned u; short s[2]; } p;
    p.s[0] = f2bf(v0); p.s[1] = f2bf(v1);
    *(unsigned*)&t[nl][c] = p.u;
  }
  __syncthreads();
  int cl = (tid & 31) * 2, nl0 = tid >> 5;
#pragma unroll
  for (int nn = 0; nn < 8; ++nn){
    int n = nl0 + nn * 8;
    *(unsigned*)&xtb[(size_t)(n0 + n) * CD + c0 + cl] = *(const unsigned*)&t[n][cl];
  }
}

// ---------------- Q/K projections ----------------
__global__ void proj_qk(const short* __restrict__ XT1, const short* __restrict__ XT2,
                        const short* __restrict__ WB,
                        const float* __restrict__ bq1, const float* __restrict__ bk1,
                        const float* __restrict__ bq2, const float* __restrict__ bk2,
                        short* __restrict__ Q1, short* __restrict__ K1,
                        short* __restrict__ Q2, short* __restrict__ K2){
  int pt = blockIdx.y;
  const short* xt = (pt < 2) ? XT1 : XT2;
  const short* w  = WB + (pt == 0 ? 0 : pt == 1 ? 32768 : pt == 2 ? 327680 : 360448);
  const float* bias = (pt == 0) ? bq1 : (pt == 1) ? bk1 : (pt == 2) ? bq2 : bk2;
  short* out = (pt == 0) ? Q1 : (pt == 1) ? K1 : (pt == 2) ? Q2 : K2;
  int row0 = blockIdx.x * 128;
  int wid = threadIdx.x >> 6, lane = threadIdx.x & 63;
  int lr = lane & 15, lk = (lane >> 4) * 8, lq4 = (lane >> 4) * 4;
  f32x4 acc[2][4] = {};
#pragma unroll 2
  for (int kk = 0; kk < 16; ++kk){
    int k0 = kk * 32 + lk;
    bf16x8 a[2], bb[4];
#pragma unroll
    for (int fr = 0; fr < 2; ++fr)
      a[fr] = *(const bf16x8*)&xt[(size_t)(row0 + wid*32 + fr*16 + lr) * CD + k0];
#pragma unroll
    for (int fc = 0; fc < 4; ++fc)
      bb[fc] = *(const bf16x8*)&w[(size_t)(fc*16 + lr) * CD + k0];
#pragma unroll
    for (int fr = 0; fr < 2; ++fr)
#pragma unroll
      for (int fc = 0; fc < 4; ++fc)
        acc[fr][fc] = __builtin_amdgcn_mfma_f32_16x16x32_bf16(a[fr], bb[fc], acc[fr][fc], 0,0,0);
  }
#pragma unroll
  for (int fr = 0; fr < 2; ++fr)
#pragma unroll
    for (int fc = 0; fc < 4; ++fc){
      int col = fc*16 + lr;
      float bsv = bias[col];
#pragma unroll
      for (int r = 0; r < 4; ++r){
        int row = row0 + wid*32 + fr*16 + lq4 + r;
        out[(size_t)row * DQV + col] = f2bf(acc[fr][fc][r] + bsv);
      }
    }
}

// ---------------- V projection ----------------
__global__ void proj_v(const short* __restrict__ XT1, const short* __restrict__ XT2,
                       const short* __restrict__ WB,
                       const float* __restrict__ bv1, const float* __restrict__ bv2,
                       short* __restrict__ V1, short* __restrict__ V2){
  int inp = blockIdx.z, b = blockIdx.y;
  int ct = blockIdx.x >> 6, nt = blockIdx.x & 63;
  const short* xt = (inp ? XT2 : XT1) + (size_t)b * NT * CD;
  const short* w  = WB + (inp ? 393216 : 65536);
  const float* bias = inp ? bv2 : bv1;
  short* V = (inp ? V2 : V1) + (size_t)b * CD * NT;
  int c0 = ct * 128, n0 = nt * 64;
  int wid = threadIdx.x >> 6, lane = threadIdx.x & 63;
  int ch = wid >> 1, nh = wid & 1;
  int lr = lane & 15, lk = (lane >> 4) * 8, lq4 = (lane >> 4) * 4;
  f32x4 acc[4][2] = {};
#pragma unroll 2
  for (int kk = 0; kk < 16; ++kk){
    int k0 = kk * 32 + lk;
    bf16x8 a[4], bb[2];
#pragma unroll
    for (int fr = 0; fr < 4; ++fr)
      a[fr] = *(const bf16x8*)&w[(size_t)(c0 + ch*64 + fr*16 + lr) * CD + k0];
#pragma unroll
    for (int fc = 0; fc < 2; ++fc)
      bb[fc] = *(const bf16x8*)&xt[(size_t)(n0 + nh*32 + fc*16 + lr) * CD + k0];
#pragma unroll
    for (int fr = 0; fr < 4; ++fr)
#pragma unroll
      for (int fc = 0; fc < 2; ++fc)
        acc[fr][fc] = __builtin_amdgcn_mfma_f32_16x16x32_bf16(a[fr], bb[fc], acc[fr][fc], 0,0,0);
  }
#pragma unroll
  for (int fr = 0; fr < 4; ++fr)
#pragma unroll
    for (int fc = 0; fc < 2; ++fc)
#pragma unroll
      for (int r = 0; r < 4; ++r){
        int c = c0 + ch*64 + fr*16 + lq4 + r;
        int n = n0 + nh*32 + fc*16 + lr;
        V[(size_t)c * NT + n] = f2bf(acc[fr][fc][r] + bias[c]);
      }
}

// ---------------- fused flash cross-attention + residual ----------------
// r2 structure + channel-split + cross-barrier prefetch:
// 1024 blocks x 512 thr; block = (pair, chalf, qb): 64 queries, 256 channels.
// Wave owns 32ch x 64q -> acc = 32 AGPR (frees 32 VGPR vs r2 for V prefetch).
// Each block reads only HALF of V => logical V traffic unchanged vs r3 (r4 lesson).
// Raw barriers (lgkmcnt-only, no vmcnt drain) let V loads issued at loop top stay
// in flight through QK+softmax (~2 phases of latency cover). 2 barriers/tile.
// Register budget (the r4/r5 spill lesson): ~76 arch VGPR + 32 AGPR < 128 cap.
__global__ void __launch_bounds__(512, 4) attn_fused(
    const short* __restrict__ Q1, const short* __restrict__ K1, const short* __restrict__ V1,
    const short* __restrict__ Q2, const short* __restrict__ K2, const short* __restrict__ V2,
    const float* __restrict__ x1, const float* __restrict__ x2,
    const float* __restrict__ g1, const float* __restrict__ g2,
    float* __restrict__ out){
  __shared__ float S[64][68];
  __shared__ __align__(16) short P[64][72];
  __shared__ float lrow[64], crow[64];

  int bid = blockIdx.x;
  int pair = bid & 7;                  // -> XCD affinity (bid%8 round-robin)
  int rest = bid >> 3;
  int chalf = rest & 1, qb = rest >> 1;   // qb in [0,64)
  int b = pair & 3, at = pair >> 2;
  const short* Q = at ? Q2 : Q1;
  const short* K = at ? K1 : K2;   // cross: queries from one stream, K/V from the other
  const short* V = at ? V1 : V2;
  const float* xr = at ? x2 : x1;
  float gamma = at ? g2[0] : g1[0];
  float* outp = out + (size_t)at * NB*CD*NT + (size_t)b * CD*NT;
  const float* xrb = xr + (size_t)b * CD*NT;
  const short* Qb = Q + ((size_t)b*NT + (size_t)qb*64) * DQV;
  const short* Kb = K + (size_t)b*NT*DQV;
  const short* Vb = V + (size_t)b*CD*NT;

  int tid = threadIdx.x, wid = tid >> 6, lane = tid & 63;
  int lr = lane & 15, lk8 = (lane >> 4) * 8, lq4 = (lane >> 4) * 4;

  // QK role: wave (ih,jq) computes S[ih*32..+31][jq*16..+15]
  int ih = wid >> 2, jq = wid & 3;
  bf16x8 qf[2][2];
#pragma unroll
  for (int fr = 0; fr < 2; ++fr)
#pragma unroll
    for (int fk = 0; fk < 2; ++fk)
      qf[fr][fk] = *(const bf16x8*)&Qb[(size_t)(ih*32 + fr*16 + lr) * DQV + fk*32 + lk8];

  f32x4 acc[2][4] = {};                // PV: wave owns 32 channels x 64 queries
  int c0 = chalf * 256 + wid * 32;
  int si = tid >> 3, sj = (tid & 7) * 8;   // softmax: 8 threads/row
  float m_reg = -1e30f, l_reg = 0.f;

#pragma unroll 1
  for (int jt = 0; jt < 64; ++jt){
    int j0 = jt * 64;
    // ---- issue V loads NOW; they fly through both barriers, consumed in PV ----
    bf16x8 vf[2][2];
#pragma unroll
    for (int cr = 0; cr < 2; ++cr)
#pragma unroll
      for (int kk = 0; kk < 2; ++kk)
        vf[cr][kk] = *(const bf16x8*)&Vb[(size_t)(c0 + cr*16 + lr) * NT + j0 + kk*32 + lk8];
    // ---- QK^T tile ----
    f32x4 s0 = {}, s1 = {};
#pragma unroll
    for (int fk = 0; fk < 2; ++fk){
      bf16x8 kf = *(const bf16x8*)&Kb[(size_t)(j0 + jq*16 + lr) * DQV + fk*32 + lk8];
      s0 = __builtin_amdgcn_mfma_f32_16x16x32_bf16(qf[0][fk], kf, s0, 0,0,0);
      s1 = __builtin_amdgcn_mfma_f32_16x16x32_bf16(qf[1][fk], kf, s1, 0,0,0);
    }
#pragma unroll
    for (int r = 0; r < 4; ++r){
      S[ih*32 + lq4 + r][jq*16 + lr]      = s0[r];
      S[ih*32 + 16 + lq4 + r][jq*16 + lr] = s1[r];
    }
    BAR();
    // ---- online softmax: max, P = exp(S-m) bf16, row sum ----
    {
      f32x4 sa = *(const f32x4*)&S[si][sj];
      f32x4 sb = *(const f32x4*)&S[si][sj + 4];
      float mx = fmaxf(fmaxf(fmaxf(sa[0], sa[1]), fmaxf(sa[2], sa[3])),
                       fmaxf(fmaxf(sb[0], sb[1]), fmaxf(sb[2], sb[3])));
      mx = fmaxf(mx, __shfl_xor(mx, 1));
      mx = fmaxf(mx, __shfl_xor(mx, 2));
      mx = fmaxf(mx, __shfl_xor(mx, 4));
      float mn = fmaxf(m_reg, mx);
      float cf = __expf(m_reg - mn);   // no-growth => exactly 1.0
      float e0 = __expf(sa[0] - mn), e1 = __expf(sa[1] - mn);
      float e2 = __expf(sa[2] - mn), e3 = __expf(sa[3] - mn);
      float e4 = __expf(sb[0] - mn), e5 = __expf(sb[1] - mn);
      float e6 = __expf(sb[2] - mn), e7 = __expf(sb[3] - mn);
      float sum = ((e0 + e1) + (e2 + e3)) + ((e4 + e5) + (e6 + e7));
      bf16x8 pv;
      pv[0] = f2bf(e0); pv[1] = f2bf(e1); pv[2] = f2bf(e2); pv[3] = f2bf(e3);
      pv[4] = f2bf(e4); pv[5] = f2bf(e5); pv[6] = f2bf(e6); pv[7] = f2bf(e7);
      *(bf16x8*)&P[si][sj] = pv;
      sum += __shfl_xor(sum, 1);
      sum += __shfl_xor(sum, 2);
      sum += __shfl_xor(sum, 4);
      l_reg = l_reg * cf + sum;
      m_reg = mn;
      if ((tid & 7) == 0) crow[si] = cf;
    }
    BAR();
    // ---- rescale accumulators (exact skip when all cf==1), PV MFMA ----
    {
      float cfa[4];
#pragma unroll
      for (int ci = 0; ci < 4; ++ci) cfa[ci] = crow[ci*16 + lr];
      bool ident = (cfa[0] == 1.f) & (cfa[1] == 1.f) & (cfa[2] == 1.f) & (cfa[3] == 1.f);
      if (!__all(ident)){
#pragma unroll
        for (int ci = 0; ci < 4; ++ci){
          float cf = cfa[ci];
#pragma unroll
          for (int cr = 0; cr < 2; ++cr){
            acc[cr][ci][0] *= cf; acc[cr][ci][1] *= cf;
            acc[cr][ci][2] *= cf; acc[cr][ci][3] *= cf;
          }
        }
      }
    }
    __builtin_amdgcn_s_setprio(1);
#pragma unroll
    for (int kk = 0; kk < 2; ++kk){
      bf16x8 pf[4];
#pragma unroll
      for (int ci = 0; ci < 4; ++ci)
        pf[ci] = *(const bf16x8*)&P[ci*16 + lr][kk*32 + lk8];
#pragma unroll
      for (int cr = 0; cr < 2; ++cr)
#pragma unroll
        for (int ci = 0; ci < 4; ++ci)
          acc[cr][ci] = __builtin_amdgcn_mfma_f32_16x16x32_bf16(vf[cr][kk], pf[ci], acc[cr][ci], 0,0,0);
    }
    __builtin_amdgcn_s_setprio(0);
    // loop edge needs no 3rd barrier: S(t+1) writes only race softmax(t) reads,
    // which each wave drained (lgkmcnt) before bar2; P(t+1) writes sit behind bar1(t+1).
  }
  // ---- publish row sums, epilogue: out = x + gamma * acc / l ----
  if ((tid & 7) == 0) lrow[si] = l_reg;
  BAR();
#pragma unroll
  for (int ci = 0; ci < 4; ++ci){
    float linv = 1.f / lrow[ci*16 + lr];
    int ig = qb*64 + ci*16 + lr;
#pragma unroll
    for (int cr = 0; cr < 2; ++cr)
#pragma unroll
      for (int r = 0; r < 4; ++r){
        int c = c0 + cr*16 + lq4 + r;
        size_t idx = (size_t)c * NT + ig;
        outp[idx] = xrb[idx] + gamma * acc[cr][ci][r] * linv;
      }
  }
}

extern "C" void kernel_launch(void* const* d_in, const int* in_sizes, int n_in,
                              void* d_out, int out_size, void* d_ws, size_t ws_size,
                              hipStream_t stream) {
  const float* x1  = (const float*)d_in[0];
  const float* x2  = (const float*)d_in[1];
  const float* wq1 = (const float*)d_in[2];
  const float* bq1 = (const float*)d_in[3];
  const float* wk1 = (const float*)d_in[4];
  const float* bk1 = (const float*)d_in[5];
  const float* wv1 = (const float*)d_in[6];
  const float* bv1 = (const float*)d_in[7];
  const float* wq2 = (const float*)d_in[8];
  const float* bq2 = (const float*)d_in[9];
  const float* wk2 = (const float*)d_in[10];
  const float* bk2 = (const float*)d_in[11];
  const float* wv2 = (const float*)d_in[12];
  const float* bv2 = (const float*)d_in[13];
  const float* g1  = (const float*)d_in[14];
  const float* g2  = (const float*)d_in[15];

  short* XT1 = (short*)d_ws;               // [4,4096,512]
  short* XT2 = XT1 + 8388608;
  short* Q1  = XT2 + 8388608;              // [4*4096,64]
  short* K1  = Q1 + 1048576;
  short* Q2  = K1 + 1048576;
  short* K2  = Q2 + 1048576;
  short* V1  = K2 + 1048576;               // [4,512,4096]
  short* V2  = V1 + 8388608;
  short* WB  = V2 + 8388608;               // cast weights

  cast_weights<<<2560, 256, 0, stream>>>(wq1, wk1, wv1, wq2, wk2, wv2, WB);
  transpose_cast<<<dim3(64, 8, 8), 256, 0, stream>>>(x1, x2, XT1, XT2);
  proj_qk<<<dim3(128, 4), 256, 0, stream>>>(XT1, XT2, WB, bq1, bk1, bq2, bk2, Q1, K1, Q2, K2);
  proj_v<<<dim3(256, 4, 2), 256, 0, stream>>>(XT1, XT2, WB, bv1, bv2, V1, V2);
  attn_fused<<<1024, 512, 0, stream>>>(Q1, K1, V1, Q2, K2, V2, x1, x2, g1, g2, (float*)d_out);
}